// Round 4
// baseline (151.843 us; speedup 1.0000x reference)
//
#include <hip/hip_runtime.h>

#define RS   100            // row stride (floats) of a 97x97 plane
#define PLS  9700           // plane stride = 97 rows * RS
#define NP   9409           // 97*97 valid elements per plane

// ws layout (float offsets)
#define OFF_R   0                           // 4*32 planes (pooled relations)
#define OFF_A   (OFF_R   + 4*32*PLS)        // 4*16 planes: A0 = r@W0f
#define OFF_Bm  (OFF_A   + 4*16*PLS)        // 4*16 planes: B0 = r@W0r
#define OFF_F1  (OFF_Bm  + 4*16*PLS)        // 4*16 planes: A1 (mpA output; F1 itself never materialized)
#define OFF_F2  (OFF_F1  + 4*16*PLS)        // unused (layout kept)
#define OFF_A1r (OFF_F2  + 4*16*PLS)        // 4*16 planes: r-part of step-1 ft projection
#define OFF_B1  (OFF_A1r + 4*16*PLS)        // 4*16 planes: B1 = r@W1r

// mp_fused LDS geometry
#define HSTR  328   // h-stride (words) in As/Bs: (328%32)=8 -> b128 reads max 2-way conflict (free)
#define KSTR  20    // k-stride (words): keeps b128 16B-aligned, spreads banks
#define FSTR  17    // inner stride of Fs[16][16][17] (conflict-breaking pad)

__device__ __forceinline__ float sigm(float x) { return 1.0f / (1.0f + __expf(-x)); }

// ---------------- interval pooling (max & min) + pad -> R planes ----------------
// v4: 2-segment scans. Each 96-step serial chain is split into two 48-step halves run
// concurrently by 192 threads, followed by a parallel fix-up pass applying the carry.
__global__ __launch_bounds__(256) void pool_kernel(const float* __restrict__ a, float* __restrict__ R) {
    __shared__ float s[96][97];
    const int tid = threadIdx.x;
    const int b  = blockIdx.x >> 5;
    const int ch = blockIdx.x & 31;
    const int d  = ch & 15;
    const bool isMin = (ch >= 16);

    for (int idx = tid; idx < 96 * 96; idx += 256) {
        int i = idx / 96, j = idx - i * 96;
        float v = a[((size_t)(b * 96 + i) * 96 + j) * 16 + d];
        if (isMin) v = -v;
        s[i][j] = (j >= i) ? v : -1e30f;
    }
    __syncthreads();

    // ---- reverse cummax over i (per column j), 2 segments ----
    if (tid < 192) {
        const int j = (tid < 96) ? tid : tid - 96;
        float run = -1e30f;
        if (tid < 96) {          // top half: rows 95..48 (final values)
#pragma unroll 4
            for (int i = 95; i >= 48; --i) { run = fmaxf(run, s[i][j]); s[i][j] = run; }
        } else {                 // bottom half: rows 47..0 (partial: max over [i,48))
#pragma unroll 4
            for (int i = 47; i >= 0; --i) { run = fmaxf(run, s[i][j]); s[i][j] = run; }
        }
    }
    __syncthreads();
    // fix-up: rows 0..47 need max with carry = s[48][j] (= max over rows 48..95)
    for (int idx = tid; idx < 48 * 96; idx += 256) {
        const int i = idx / 96, j = idx - i * 96;
        s[i][j] = fmaxf(s[i][j], s[48][j]);
    }
    __syncthreads();

    // ---- forward cummax over j (per row i), 2 segments ----
    if (tid < 192) {
        const int i = (tid < 96) ? tid : tid - 96;
        float run = -1e30f;
        if (tid < 96) {          // first half: cols 0..47 (final values)
#pragma unroll 4
            for (int j = 0; j < 48; ++j) { run = fmaxf(run, s[i][j]); s[i][j] = run; }
        } else {                 // second half: cols 48..95 (partial)
#pragma unroll 4
            for (int j = 48; j < 96; ++j) { run = fmaxf(run, s[i][j]); s[i][j] = run; }
        }
    }
    __syncthreads();
    // fix-up: cols 48..95 need max with carry = s[i][47]
    for (int idx = tid; idx < 96 * 48; idx += 256) {
        const int i = idx / 48, j = 48 + (idx - i * 48);
        s[i][j] = fmaxf(s[i][j], s[i][47]);
    }
    __syncthreads();

    float* Rp = R + (size_t)blockIdx.x * PLS;
    for (int idx = tid; idx < 97 * 97; idx += 256) {
        int x = idx / 97, y = idx - x * 97;
        float v = 0.f;
        if (x <= 95 && y >= 1 && x <= y - 1) { v = s[x][y - 1]; if (isMin) v = -v; }
        Rp[x * RS + y] = v;
    }
}

// ---------------- projections that depend only on R (unchanged, proven) ----------------
__global__ __launch_bounds__(256) void projA_kernel(const float* __restrict__ R,
                                                    const float* __restrict__ W0, const float* __restrict__ W1,
                                                    float* __restrict__ A0, float* __restrict__ B0,
                                                    float* __restrict__ A1r, float* __restrict__ B1) {
    const int by = blockIdx.y, b = by >> 3, hp = by & 7;
    const int h0 = hp * 2, h1 = h0 + 1;
    const int p = blockIdx.x * 256 + threadIdx.x;
    if (p >= NP) return;
    const int x = p / 97, y = p - x * 97;
    const int off = x * RS + y;
    const float* Rb = R + (size_t)b * 32 * PLS + off;
    float aA00 = 0.f, aA01 = 0.f, aB00 = 0.f, aB01 = 0.f;
    float aA10 = 0.f, aA11 = 0.f, aB10 = 0.f, aB11 = 0.f;
#pragma unroll
    for (int d = 0; d < 32; ++d) {
        const float rv = Rb[(size_t)d * PLS];
        aA00 += rv * W0[d * 16 + h0];
        aA01 += rv * W0[d * 16 + h1];
        aB00 += rv * W0[(32 + d) * 16 + h0];
        aB01 += rv * W0[(32 + d) * 16 + h1];
        aA10 += rv * W1[(16 + d) * 16 + h0];
        aA11 += rv * W1[(16 + d) * 16 + h1];
        aB10 += rv * W1[(48 + d) * 16 + h0];
        aB11 += rv * W1[(48 + d) * 16 + h1];
    }
    const size_t o0 = (size_t)(b * 16 + h0) * PLS + off;
    const size_t o1 = (size_t)(b * 16 + h1) * PLS + off;
    A0 [o0] = aA00;  A0 [o1] = aA01;
    B0 [o0] = aB00;  B0 [o1] = aB01;
    A1r[o0] = aA10;  A1r[o1] = aA11;
    B1 [o0] = aB10;  B1 [o1] = aB11;
}

// ---------------- fused all-h maxplus + pointwise epilogue (unchanged from R3, proven) ----------------
template<bool LAST>
__global__ __launch_bounds__(256) void mp_fused(
    const float* __restrict__ A, const float* __restrict__ B,
    const float* __restrict__ biasv,          // b0 / b1
    const float* __restrict__ Wx,             // LAST ? W2 (48x16) : W1 (rows 0..15 used)
    const float* __restrict__ Aux,            // LAST ? R base : A1r base
    const float* __restrict__ bias2,          // LAST ? b2 : unused
    float* __restrict__ Out)                  // LAST ? out : A1 planes
{
    __shared__ float As[16 * HSTR];           // As[h][k][i] (transposed), one 16-k chunk
    __shared__ float Bs[16 * HSTR];           // Bs[h][k][j]
    __shared__ float Fs[16 * 16 * FSTR];      // F tile, all 16 channels
    __shared__ float Ws[768];                 // staged weights (256 or 768 used)

    const int tid = threadIdx.x;
    const int b  = blockIdx.y;
    const int ti = blockIdx.x / 7, tj = blockIdx.x % 7;
    const int i0 = ti * 16, j0 = tj * 16;
    const int h  = tid >> 4, q = tid & 15;
    const int iq = q >> 2, jq = q & 3;

    {   // stage weights (consumed only after later barriers)
        const int nw = LAST ? 768 : 256;
        for (int s = tid; s < nw; s += 256) Ws[s] = Wx[s];
    }

    const float* Ab = A + (size_t)(b * 16 + h) * PLS;
    const float* Bb = B + (size_t)(b * 16 + h) * PLS;

    float4 Ar[4], Br[4];                      // reg double-buffer for one 16-k chunk

    auto load_chunk = [&](int kc) {
#pragma unroll
        for (int t = 0; t < 4; ++t) {
            const int s  = t * 256 + tid;
            const int h2 = s >> 6;            // plane channel
            const int m2 = (s >> 2) & 15;     // A: i index | B: k index
            const int q2 = s & 3;             // A: k-quad  | B: j-quad
            const float* Ap = A + (size_t)(b * 16 + h2) * PLS;
            const int row = i0 + m2;
            if (row <= 96) Ar[t] = *reinterpret_cast<const float4*>(&Ap[row * RS + kc + q2 * 4]);
            else           Ar[t] = make_float4(-1e30f, -1e30f, -1e30f, -1e30f);
            const float* Bp = B + (size_t)(b * 16 + h2) * PLS;
            const int colq = j0 + q2 * 4;
            if (colq + 3 <= 96) {
                Br[t] = *reinterpret_cast<const float4*>(&Bp[(kc + m2) * RS + colq]);
            } else {
                float v[4];
#pragma unroll
                for (int e = 0; e < 4; ++e) {
                    const int col = colq + e;
                    v[e] = (col <= 96) ? Bp[(kc + m2) * RS + col] : -1e30f;
                }
                Br[t] = make_float4(v[0], v[1], v[2], v[3]);
            }
        }
    };
    auto store_chunk = [&]() {
#pragma unroll
        for (int t = 0; t < 4; ++t) {
            const int s  = t * 256 + tid;
            const int h2 = s >> 6;
            const int m2 = (s >> 2) & 15;
            const int q2 = s & 3;
            float* as = &As[h2 * HSTR + m2];              // A transposed: [h][k][i]
            as[(q2 * 4 + 0) * KSTR] = Ar[t].x;
            as[(q2 * 4 + 1) * KSTR] = Ar[t].y;
            as[(q2 * 4 + 2) * KSTR] = Ar[t].z;
            as[(q2 * 4 + 3) * KSTR] = Ar[t].w;
            *reinterpret_cast<float4*>(&Bs[h2 * HSTR + m2 * KSTR + q2 * 4]) = Br[t];  // B direct: [h][k][j]
        }
    };

    float acc[4][4];
#pragma unroll
    for (int r = 0; r < 4; ++r)
#pragma unroll
        for (int c = 0; c < 4; ++c) acc[r][c] = -1e30f;

    auto compute_k = [&](int k) {
        const float4 av = *reinterpret_cast<const float4*>(&As[h * HSTR + k * KSTR + iq * 4]);
        const float4 bv = *reinterpret_cast<const float4*>(&Bs[h * HSTR + k * KSTR + jq * 4]);
        const float aa[4] = {av.x, av.y, av.z, av.w};
        const float bb[4] = {bv.x, bv.y, bv.z, bv.w};
#pragma unroll
        for (int r = 0; r < 4; ++r)
#pragma unroll
            for (int c = 0; c < 4; ++c) acc[r][c] = fmaxf(acc[r][c], aa[r] + bb[c]);
    };

    // ---- main loop: 6 chunks of 16 k, reg-double-buffered; then edge k=96 ----
    load_chunk(0);
    store_chunk();
    __syncthreads();
    for (int c = 0; c < 6; ++c) {
        if (c < 5) load_chunk((c + 1) * 16);  // issue next-chunk loads before compute (hide latency)
#pragma unroll
        for (int k = 0; k < 16; ++k) compute_k(k);
        __syncthreads();                      // LDS reads done
        if (c < 5) { store_chunk(); __syncthreads(); }
    }
    // edge column k = 96 (reuse k-slot 0 of both panels)
    As[h * HSTR + q] = (i0 + q <= 96) ? Ab[(i0 + q) * RS + 96] : -1e30f;
    Bs[h * HSTR + q] = (j0 + q <= 96) ? Bb[96 * RS + (j0 + q)] : -1e30f;
    __syncthreads();
    compute_k(0);

    // ---- F tile (all 16 channels) -> LDS ----
    const float bbia = biasv[h];
#pragma unroll
    for (int r = 0; r < 4; ++r)
#pragma unroll
        for (int c = 0; c < 4; ++c)
            Fs[h * (16 * FSTR) + (iq * 4 + r) * FSTR + (jq * 4 + c)] = sigm(acc[r][c] + bbia);
    __syncthreads();

    if (!LAST) {
        // ---- projF fused: A1[h] = A1r[h] + sum_c F1[c]*W1[c][h], per tile point ----
        const float* Axr = Aux + (size_t)(b * 16 + h) * PLS;
        float* Ob = Out + (size_t)(b * 16 + h) * PLS;
        const int ybase = j0 + jq * 4;
        const bool fullq = (ybase + 3 <= 96);
#pragma unroll
        for (int r = 0; r < 4; ++r) {
            const int x = i0 + iq * 4 + r;
            if (x > 96) continue;
            float o4[4];
            if (fullq) {
                const float4 t4 = *reinterpret_cast<const float4*>(&Axr[x * RS + ybase]);
                o4[0] = t4.x; o4[1] = t4.y; o4[2] = t4.z; o4[3] = t4.w;
            } else {
#pragma unroll
                for (int e = 0; e < 4; ++e) o4[e] = (ybase + e <= 96) ? Axr[x * RS + ybase + e] : 0.f;
            }
#pragma unroll
            for (int c16 = 0; c16 < 16; ++c16) {
                const float w = Ws[c16 * 16 + h];
                const float* fr = &Fs[c16 * (16 * FSTR) + (iq * 4 + r) * FSTR + jq * 4];
                o4[0] += fr[0] * w; o4[1] += fr[1] * w; o4[2] += fr[2] * w; o4[3] += fr[3] * w;
            }
            if (fullq) {
                *reinterpret_cast<float4*>(&Ob[x * RS + ybase]) = make_float4(o4[0], o4[1], o4[2], o4[3]);
            } else {
#pragma unroll
                for (int e = 0; e < 4; ++e) if (ybase + e <= 96) Ob[x * RS + ybase + e] = o4[e];
            }
        }
    } else {
        // ---- final fused: thread = tile point; out = sigm([F2,r]@W2 + b2), cropped ----
        const int pi = tid >> 4, pj = tid & 15;
        const int x = i0 + pi, y = j0 + pj;
        if (x <= 95 && y >= 1 && y <= 96) {
            const float* Rb = Aux + (size_t)b * 32 * PLS + x * RS + y;
            float o[16];
#pragma unroll
            for (int oo = 0; oo < 16; ++oo) o[oo] = bias2[oo];
#pragma unroll
            for (int c = 0; c < 16; ++c) {
                const float fv = Fs[c * (16 * FSTR) + pi * FSTR + pj];
#pragma unroll
                for (int oo = 0; oo < 16; ++oo) o[oo] += fv * Ws[c * 16 + oo];
            }
#pragma unroll
            for (int d = 0; d < 32; ++d) {
                const float rv = Rb[(size_t)d * PLS];
#pragma unroll
                for (int oo = 0; oo < 16; ++oo) o[oo] += rv * Ws[(16 + d) * 16 + oo];
            }
            float* dst = Out + ((size_t)((b * 96 + x) * 96) + (y - 1)) * 16;
#pragma unroll
            for (int qd = 0; qd < 4; ++qd) {
                float4 v;
                v.x = sigm(o[qd * 4 + 0]);
                v.y = sigm(o[qd * 4 + 1]);
                v.z = sigm(o[qd * 4 + 2]);
                v.w = sigm(o[qd * 4 + 3]);
                *reinterpret_cast<float4*>(&dst[qd * 4]) = v;
            }
        }
    }
}

extern "C" void kernel_launch(void* const* d_in, const int* in_sizes, int n_in,
                              void* d_out, int out_size, void* d_ws, size_t ws_size,
                              hipStream_t stream) {
    const float* a  = (const float*)d_in[0];
    const float* W0 = (const float*)d_in[1];
    const float* b0 = (const float*)d_in[2];
    const float* W1 = (const float*)d_in[3];
    const float* b1 = (const float*)d_in[4];
    const float* W2 = (const float*)d_in[5];
    const float* b2 = (const float*)d_in[6];
    float* ws  = (float*)d_ws;
    float* out = (float*)d_out;

    hipLaunchKernelGGL(pool_kernel, dim3(128), dim3(256), 0, stream, a, ws + OFF_R);
    hipLaunchKernelGGL(projA_kernel, dim3(37, 32), dim3(256), 0, stream,
                       ws + OFF_R, W0, W1, ws + OFF_A, ws + OFF_Bm, ws + OFF_A1r, ws + OFF_B1);
    hipLaunchKernelGGL((mp_fused<false>), dim3(49, 4), dim3(256), 0, stream,
                       ws + OFF_A, ws + OFF_Bm, b0, W1, ws + OFF_A1r, b0, ws + OFF_F1);
    hipLaunchKernelGGL((mp_fused<true>), dim3(49, 4), dim3(256), 0, stream,
                       ws + OFF_F1, ws + OFF_B1, b1, W2, ws + OFF_R, b2, out);
}